// Round 2
// baseline (361.470 us; speedup 1.0000x reference)
//
#include <hip/hip_runtime.h>
#include <cstdint>
#include <cstddef>

#define BB 4
#define NN 1024
#define EMB_ 64
#define NH_ 8
#define BH_ (BB*NH_)
#define HID_ 256
#define K_ 8
#define NPTS_ 64

// ---------------- threefry2x32 (JAX-compatible, 20 rounds) ----------------
__host__ __device__ inline void tf2x32(uint32_t k0, uint32_t k1, uint32_t c0, uint32_t c1,
                                       uint32_t &o0, uint32_t &o1) {
  uint32_t ks2 = k0 ^ k1 ^ 0x1BD11BDAu;
  uint32_t x0 = c0 + k0, x1 = c1 + k1;
#define TFR(r) { x0 += x1; x1 = (x1 << (r)) | (x1 >> (32 - (r))); x1 ^= x0; }
  TFR(13) TFR(15) TFR(26) TFR(6)
  x0 += k1;  x1 += ks2 + 1u;
  TFR(17) TFR(29) TFR(16) TFR(24)
  x0 += ks2; x1 += k0 + 2u;
  TFR(13) TFR(15) TFR(26) TFR(6)
  x0 += k0;  x1 += k1 + 3u;
  TFR(17) TFR(29) TFR(16) TFR(24)
  x0 += k1;  x1 += ks2 + 4u;
  TFR(13) TFR(15) TFR(26) TFR(6)
  x0 += ks2; x1 += k0 + 5u;
#undef TFR
  o0 = x0; o1 = x1;
}

// partitionable random_bits, 32-bit: y0 ^ y1 of TF(key, (0, flat_index))
__device__ inline uint32_t tf_bits(uint32_t k0, uint32_t k1, uint32_t idx) {
  uint32_t a, b;
  tf2x32(k0, k1, 0u, idx, a, b);
  return a ^ b;
}

__device__ inline float softplusf(float v) {
  return fmaxf(v, 0.f) + log1pf(expf(-fabsf(v)));
}

// ---------------- K1: QKV projection ----------------
#define ROWS1 16
__global__ void qkv_kernel(const float* __restrict__ x,
                           const float* __restrict__ Wq, const float* __restrict__ Wk,
                           const float* __restrict__ Wv,
                           float* __restrict__ q, float* __restrict__ k, float* __restrict__ v) {
  __shared__ float xs[ROWS1][EMB_];
  const int block0 = blockIdx.x * ROWS1; // global row (b*N+n)
  const int t = threadIdx.x;             // 256 threads
  for (int i = t; i < ROWS1 * EMB_; i += 256) xs[i / EMB_][i % EMB_] = x[(size_t)block0 * EMB_ + i];
  __syncthreads();
  const float qkscale = 0.3535533905932738f; // 64^-0.25

  auto dmat = [&](const float* __restrict__ W, float* __restrict__ o, float sc) {
    for (int half = 0; half < 2; half++) {
      const int c = half * 256 + t; // 0..511
      float acc[ROWS1];
#pragma unroll
      for (int r = 0; r < ROWS1; r++) acc[r] = 0.f;
      for (int i = 0; i < EMB_; i++) {
        const float wv = W[i * 512 + c];
#pragma unroll
        for (int r = 0; r < ROWS1; r++) acc[r] += xs[r][i] * wv;
      }
      const int h = c >> 6, j = c & 63;
#pragma unroll
      for (int r = 0; r < ROWS1; r++) {
        const int gr = block0 + r;
        const int b = gr >> 10, n = gr & 1023;
        o[(((size_t)(b * NH_ + h) * NN + n)) * EMB_ + j] = acc[r] * sc;
      }
    }
  };
  dmat(Wq, q, qkscale);
  dmat(Wk, k, qkscale);
  dmat(Wv, v, 1.0f);
}

// ---------------- K2: MLP + point generation + weights ----------------
__global__ void points_kernel(const float* __restrict__ x,
                              const float* __restrict__ Wp1, const float* __restrict__ bp1,
                              const float* __restrict__ Wp2, const float* __restrict__ bp2,
                              const float* __restrict__ mvalues,
                              int* __restrict__ prc, float* __restrict__ pw,
                              int* __restrict__ counts,
                              uint32_t kg0, uint32_t kg1, uint32_t kl0, uint32_t kl1) {
  __shared__ float xs[EMB_];
  __shared__ float hs[HID_];
  __shared__ float ps[16];
  __shared__ float meanv[K_], invsig[K_];
  __shared__ int flv[K_];
  __shared__ int pk[NPTS_];

  const int bn = blockIdx.x;          // b*N + n
  const int b = bn >> 10, n = bn & 1023;
  const int lane = threadIdx.x;       // 64 threads

  xs[lane] = x[(size_t)bn * EMB_ + lane];
  __syncthreads();

#pragma unroll
  for (int cc = 0; cc < 4; cc++) {
    const int c = cc * 64 + lane;
    float a = bp1[c];
    for (int i = 0; i < EMB_; i++) a += xs[i] * Wp1[i * HID_ + c];
    hs[c] = fmaxf(a, 0.f);
  }
  __syncthreads();

  if (lane < 16) {
    float a = bp2[lane];
    for (int c = 0; c < HID_; c++) a += hs[c] * Wp2[c * 16 + lane];
    ps[lane] = a;
  }
  __syncthreads();

  if (lane < K_) {
    const float rm = ps[lane], rs = ps[K_ + lane];
    float mean = (float)n - softplusf(rm);
    mean = fminf(fmaxf(mean, 0.f), (float)(NN - 1));
    const float sig = softplusf(rs + 2.0f) + 1e-6f;
    meanv[lane] = mean;
    invsig[lane] = 1.f / sig;
    flv[lane] = (int)floorf(mean);
  }
  __syncthreads();

  const int kk = lane >> 3, j = lane & 7;
  const int fl = flv[kk];
  int row, col;
  if (j < 4) {
    row = fl + (j >> 1);
    col = fl + (j & 1);
  } else if (j < 6) {
    const int g = j - 4;
    const uint32_t base = ((uint32_t)(bn * K_ + kk) * 2u + (uint32_t)g) * 2u;
    row = (int)(tf_bits(kg0, kg1, base + 0u) & 1023u);
    col = (int)(tf_bits(kg0, kg1, base + 1u) & 1023u);
  } else {
    const int a = j - 6;
    const uint32_t base = ((uint32_t)(bn * K_ + kk) * 2u + (uint32_t)a) * 2u;
    row = fl - 1 + (int)(tf_bits(kl0, kl1, base + 0u) & 1u);
    col = fl - 1 + (int)(tf_bits(kl0, kl1, base + 1u) & 1u);
  }
  row = min(max(row, 0), NN - 1);
  col = min(max(col, 0), NN - 1);
  const int packed = (row << 16) | col;
  pk[lane] = packed;
  __syncthreads();

  bool dup = false;
  for (int p2 = 0; p2 < lane; p2++)
    if (pk[p2] == packed) dup = true;

  const float frow = (float)row, fcol = (float)col;
  float dens[K_];
#pragma unroll
  for (int qd = 0; qd < K_; qd++) {
    const float dx = (frow - meanv[qd]) * invsig[qd];
    const float dy = (fcol - meanv[qd]) * invsig[qd];
    dens[qd] = dup ? 0.f : expf(-0.5f * (dx * dx + dy * dy));
  }
  float wsum = 0.f;
#pragma unroll
  for (int qd = 0; qd < K_; qd++) {
    float s = dens[qd];
    for (int d = 1; d < 64; d <<= 1) s += __shfl_xor(s, d);
    wsum += dens[qd] / s;
  }
  const float w = mvalues[n] * wsum;

  prc[(size_t)bn * NPTS_ + lane] = packed;
  pw[(size_t)bn * NPTS_ + lane] = w;
  atomicAdd(&counts[b * NN + row], 1);
}

// ---------------- K3: per-b exclusive scan of row counts ----------------
__global__ void scan_kernel(const int* __restrict__ counts,
                            int* __restrict__ offs, int* __restrict__ cursor) {
  __shared__ int sd[NN];
  const int b = blockIdx.x, t = threadIdx.x; // 1024 threads
  const int v = counts[b * NN + t];
  sd[t] = v;
  __syncthreads();
  for (int d = 1; d < NN; d <<= 1) {
    const int add = (t >= d) ? sd[t - d] : 0;
    __syncthreads();
    sd[t] += add;
    __syncthreads();
  }
  const int excl = sd[t] - v;
  offs[b * NN + t] = excl;
  cursor[b * NN + t] = excl;
}

// ---------------- K4: scatter entries into row-sorted order ----------------
__global__ void scatter_kernel(const int* __restrict__ prc, const float* __restrict__ pw,
                               int* __restrict__ cursor,
                               int* __restrict__ scol, float* __restrict__ sw) {
  const int bn = blockIdx.x;
  const int b = bn >> 10;
  const size_t i = (size_t)bn * NPTS_ + threadIdx.x;
  const int packed = prc[i];
  const int row = packed >> 16, col = packed & 0xFFFF;
  const int pos = atomicAdd(&cursor[b * NN + row], 1);
  scol[(size_t)b * (NN * NPTS_) + pos] = col;
  sw[(size_t)b * (NN * NPTS_) + pos] = pw[i];
}

// ---------------- K5: chunked two-phase flash segment softmax ----------------
// block = (b,row); 8 waves, one per head. Phase A: lane=entry, gather K row,
// dot vs q (LDS), one expf per entry. Phase B: lane=dim, readlane-broadcast
// p/col, coalesced V row loads.
__global__ void __launch_bounds__(512) attn_kernel(
    const float* __restrict__ q, const float* __restrict__ k, const float* __restrict__ v,
    const int* __restrict__ offs, const int* __restrict__ counts,
    const int* __restrict__ scol, const float* __restrict__ sw,
    float* __restrict__ attn) {
  __shared__ float qs[NH_][EMB_];
  const int bn = blockIdx.x;           // b*N + row
  const int b = bn >> 10, row = bn & 1023;
  const int h = threadIdx.x >> 6, lane = threadIdx.x & 63;
  const int bh = b * NH_ + h;

  const float* __restrict__ kb = k + (size_t)bh * NN * EMB_;
  const float* __restrict__ vb = v + (size_t)bh * NN * EMB_;
  const int* __restrict__ sc = scol + (size_t)b * (NN * NPTS_);
  const float* __restrict__ swp = sw + (size_t)b * (NN * NPTS_);

  qs[h][lane] = q[((size_t)bh * NN + row) * EMB_ + lane];
  const int start = offs[b * NN + row];
  const int len = counts[b * NN + row];
  __syncthreads();

  float m = -INFINITY, Z = 0.f, acc = 0.f;

  for (int cb = 0; cb < len; cb += 64) {
    const int e = cb + lane;
    float logit = -INFINITY;
    int col = 0;
    if (e < len) {
      col = sc[start + e];
      const float wv = swp[start + e];
      const float4* __restrict__ kp = (const float4*)(kb + (size_t)col * EMB_);
      const float4* __restrict__ qp = (const float4*)qs[h];
      float dot = 0.f;
#pragma unroll
      for (int i = 0; i < 16; i++) {
        const float4 a4 = qp[i];
        const float4 b4 = kp[i];
        dot += a4.x * b4.x + a4.y * b4.y + a4.z * b4.z + a4.w * b4.w;
      }
      logit = wv * dot;
    }
    // chunk max over 64 lanes
    float cm = logit;
#pragma unroll
    for (int d = 1; d < 64; d <<= 1) cm = fmaxf(cm, __shfl_xor(cm, d));
    const float nm = fmaxf(m, cm);               // finite (>=1 valid entry)
    const float scale = expf(m - nm);            // 0 when m was -inf
    const float p = expf(logit - nm);            // 0 for e >= len
    float zs = p;
#pragma unroll
    for (int d = 1; d < 64; d <<= 1) zs += __shfl_xor(zs, d);
    Z = Z * scale + zs;
    m = nm;

    // Phase B: accumulate V. lane = dim. p/col broadcast from lane ee.
    acc *= scale;
    const int chunkn = min(64, len - cb);
    for (int ee = 0; ee < chunkn; ee++) {
      const float pe = __shfl(p, ee);            // uniform index -> readlane
      const int ce = __shfl(col, ee);
      acc += pe * vb[(size_t)ce * EMB_ + lane];
    }
  }

  const float o = (len > 0) ? acc / Z : 0.f;
  attn[((size_t)bh * NN + row) * EMB_ + lane] = o;
}

// ---------------- K6: output projection ----------------
#define ROWS6 8
__global__ void out_kernel(const float* __restrict__ attn,
                           const float* __restrict__ Wu, const float* __restrict__ bu,
                           float* __restrict__ out) {
  __shared__ float a[ROWS6][NH_ * EMB_];
  const int base = blockIdx.x * ROWS6;
  const int lane = threadIdx.x; // 64
  for (int r = 0; r < ROWS6; r++) {
    const int bn = base + r;
    const int b = bn >> 10, n = bn & 1023;
    for (int h = 0; h < NH_; h++)
      a[r][h * EMB_ + lane] = attn[((size_t)(b * NH_ + h) * NN + n) * EMB_ + lane];
  }
  __syncthreads();
  float acc[ROWS6];
#pragma unroll
  for (int r = 0; r < ROWS6; r++) acc[r] = bu[lane];
  for (int c = 0; c < NH_ * EMB_; c++) {
    const float wv = Wu[c * EMB_ + lane];
#pragma unroll
    for (int r = 0; r < ROWS6; r++) acc[r] += a[r][c] * wv;
  }
  for (int r = 0; r < ROWS6; r++) out[(size_t)(base + r) * EMB_ + lane] = acc[r];
}

// ---------------- host ----------------
extern "C" void kernel_launch(void* const* d_in, const int* in_sizes, int n_in,
                              void* d_out, int out_size, void* d_ws, size_t ws_size,
                              hipStream_t stream) {
  const float* x   = (const float*)d_in[0];
  const float* Wq  = (const float*)d_in[1];
  const float* Wk  = (const float*)d_in[2];
  const float* Wv  = (const float*)d_in[3];
  const float* Wu  = (const float*)d_in[4];
  const float* bu  = (const float*)d_in[5];
  const float* Wp1 = (const float*)d_in[6];
  const float* bp1 = (const float*)d_in[7];
  const float* Wp2 = (const float*)d_in[8];
  const float* bp2 = (const float*)d_in[9];
  const float* mv  = (const float*)d_in[10];
  float* out = (float*)d_out;

  char* ws = (char*)d_ws;
  size_t off = 0;
  auto alloc = [&](size_t bytes) -> void* {
    void* p = ws + off;
    off += (bytes + 255) & ~(size_t)255;
    return p;
  };
  const size_t QKV = (size_t)BH_ * NN * EMB_ * sizeof(float); // 8 MB
  float* q    = (float*)alloc(QKV);
  float* k    = (float*)alloc(QKV);
  float* v    = (float*)alloc(QKV);
  float* attn = (float*)alloc(QKV);
  int*   prc  = (int*)  alloc((size_t)BB * NN * NPTS_ * sizeof(int));
  float* pw   = (float*)alloc((size_t)BB * NN * NPTS_ * sizeof(float));
  int*   counts = (int*)alloc((size_t)BB * NN * sizeof(int));
  int*   offsA  = (int*)alloc((size_t)BB * NN * sizeof(int));
  int*   cursor = (int*)alloc((size_t)BB * NN * sizeof(int));
  int*   scol = (int*)  alloc((size_t)BB * NN * NPTS_ * sizeof(int));
  float* sw   = (float*)alloc((size_t)BB * NN * NPTS_ * sizeof(float));
  if (off > ws_size) return;

  uint32_t kgA, kgB, klA, klB;
  tf2x32(0u, 42u, 0u, 0u, kgA, kgB);  // kg
  tf2x32(0u, 42u, 0u, 1u, klA, klB);  // kl
  uint32_t kg2A, kg2B, kl2A, kl2B;
  tf2x32(kgA, kgB, 0u, 1u, kg2A, kg2B); // split(kg)[1]
  tf2x32(klA, klB, 0u, 1u, kl2A, kl2B); // split(kl)[1]

  hipMemsetAsync(counts, 0, (size_t)BB * NN * sizeof(int), stream);

  qkv_kernel<<<(BB * NN) / ROWS1, 256, 0, stream>>>(x, Wq, Wk, Wv, q, k, v);
  points_kernel<<<BB * NN, 64, 0, stream>>>(x, Wp1, bp1, Wp2, bp2, mv,
                                            prc, pw, counts, kg2A, kg2B, kl2A, kl2B);
  scan_kernel<<<BB, NN, 0, stream>>>(counts, offsA, cursor);
  scatter_kernel<<<BB * NN, NPTS_, 0, stream>>>(prc, pw, cursor, scol, sw);
  attn_kernel<<<BB * NN, 512, 0, stream>>>(q, k, v, offsA, counts, scol, sw, attn);
  out_kernel<<<(BB * NN) / ROWS6, 64, 0, stream>>>(attn, Wu, bu, out);
}

// Round 3
// 273.875 us; speedup vs baseline: 1.3198x; 1.3198x over previous
//
#include <hip/hip_runtime.h>
#include <cstdint>
#include <cstddef>

#define BB 4
#define NN 1024
#define EMB_ 64
#define NH_ 8
#define BH_ (BB*NH_)
#define HID_ 256
#define K_ 8
#define NPTS_ 64

// ---------------- threefry2x32 (JAX-compatible, 20 rounds) ----------------
__host__ __device__ inline void tf2x32(uint32_t k0, uint32_t k1, uint32_t c0, uint32_t c1,
                                       uint32_t &o0, uint32_t &o1) {
  uint32_t ks2 = k0 ^ k1 ^ 0x1BD11BDAu;
  uint32_t x0 = c0 + k0, x1 = c1 + k1;
#define TFR(r) { x0 += x1; x1 = (x1 << (r)) | (x1 >> (32 - (r))); x1 ^= x0; }
  TFR(13) TFR(15) TFR(26) TFR(6)
  x0 += k1;  x1 += ks2 + 1u;
  TFR(17) TFR(29) TFR(16) TFR(24)
  x0 += ks2; x1 += k0 + 2u;
  TFR(13) TFR(15) TFR(26) TFR(6)
  x0 += k0;  x1 += k1 + 3u;
  TFR(17) TFR(29) TFR(16) TFR(24)
  x0 += k1;  x1 += ks2 + 4u;
  TFR(13) TFR(15) TFR(26) TFR(6)
  x0 += ks2; x1 += k0 + 5u;
#undef TFR
  o0 = x0; o1 = x1;
}

__device__ inline uint32_t tf_bits(uint32_t k0, uint32_t k1, uint32_t idx) {
  uint32_t a, b;
  tf2x32(k0, k1, 0u, idx, a, b);
  return a ^ b;
}

__device__ inline float softplusf(float v) {
  return fmaxf(v, 0.f) + log1pf(expf(-fabsf(v)));
}

// ---------------- K1: QKV projection ----------------
#define ROWS1 8
__global__ void qkv_kernel(const float* __restrict__ x,
                           const float* __restrict__ Wq, const float* __restrict__ Wk,
                           const float* __restrict__ Wv,
                           float* __restrict__ q, float* __restrict__ k, float* __restrict__ v) {
  __shared__ float xs[ROWS1][EMB_];
  const int block0 = blockIdx.x * ROWS1; // global row (b*N+n)
  const int t = threadIdx.x;             // 256 threads
  for (int i = t; i < ROWS1 * EMB_; i += 256) xs[i / EMB_][i % EMB_] = x[(size_t)block0 * EMB_ + i];
  __syncthreads();
  const float qkscale = 0.3535533905932738f; // 64^-0.25

  auto dmat = [&](const float* __restrict__ W, float* __restrict__ o, float sc) {
    for (int half = 0; half < 2; half++) {
      const int c = half * 256 + t; // 0..511
      float acc[ROWS1];
#pragma unroll
      for (int r = 0; r < ROWS1; r++) acc[r] = 0.f;
      for (int i = 0; i < EMB_; i++) {
        const float wv = W[i * 512 + c];
#pragma unroll
        for (int r = 0; r < ROWS1; r++) acc[r] += xs[r][i] * wv;
      }
      const int h = c >> 6, j = c & 63;
#pragma unroll
      for (int r = 0; r < ROWS1; r++) {
        const int gr = block0 + r;
        const int b = gr >> 10, n = gr & 1023;
        o[(((size_t)(b * NH_ + h) * NN + n)) * EMB_ + j] = acc[r] * sc;
      }
    }
  };
  dmat(Wq, q, qkscale);
  dmat(Wk, k, qkscale);
  dmat(Wv, v, 1.0f);
}

// ---------------- K2: MLP + point generation + weights ----------------
__global__ void points_kernel(const float* __restrict__ x,
                              const float* __restrict__ Wp1, const float* __restrict__ bp1,
                              const float* __restrict__ Wp2, const float* __restrict__ bp2,
                              const float* __restrict__ mvalues,
                              int* __restrict__ prc, float* __restrict__ pw,
                              int* __restrict__ counts,
                              uint32_t kg0, uint32_t kg1, uint32_t kl0, uint32_t kl1) {
  __shared__ float xs[EMB_];
  __shared__ float hs[HID_];
  __shared__ float ps[16];
  __shared__ float meanv[K_], invsig[K_];
  __shared__ int flv[K_];
  __shared__ int pk[NPTS_];

  const int bn = blockIdx.x;          // b*N + n
  const int b = bn >> 10, n = bn & 1023;
  const int lane = threadIdx.x;       // 64 threads

  xs[lane] = x[(size_t)bn * EMB_ + lane];
  __syncthreads();

#pragma unroll
  for (int cc = 0; cc < 4; cc++) {
    const int c = cc * 64 + lane;
    float a = bp1[c];
    for (int i = 0; i < EMB_; i++) a += xs[i] * Wp1[i * HID_ + c];
    hs[c] = fmaxf(a, 0.f);
  }
  __syncthreads();

  if (lane < 16) {
    float a = bp2[lane];
    for (int c = 0; c < HID_; c++) a += hs[c] * Wp2[c * 16 + lane];
    ps[lane] = a;
  }
  __syncthreads();

  if (lane < K_) {
    const float rm = ps[lane], rs = ps[K_ + lane];
    float mean = (float)n - softplusf(rm);
    mean = fminf(fmaxf(mean, 0.f), (float)(NN - 1));
    const float sig = softplusf(rs + 2.0f) + 1e-6f;
    meanv[lane] = mean;
    invsig[lane] = 1.f / sig;
    flv[lane] = (int)floorf(mean);
  }
  __syncthreads();

  const int kk = lane >> 3, j = lane & 7;
  const int fl = flv[kk];
  int row, col;
  if (j < 4) {
    row = fl + (j >> 1);
    col = fl + (j & 1);
  } else if (j < 6) {
    const int g = j - 4;
    const uint32_t base = ((uint32_t)(bn * K_ + kk) * 2u + (uint32_t)g) * 2u;
    row = (int)(tf_bits(kg0, kg1, base + 0u) & 1023u);
    col = (int)(tf_bits(kg0, kg1, base + 1u) & 1023u);
  } else {
    const int a = j - 6;
    const uint32_t base = ((uint32_t)(bn * K_ + kk) * 2u + (uint32_t)a) * 2u;
    row = fl - 1 + (int)(tf_bits(kl0, kl1, base + 0u) & 1u);
    col = fl - 1 + (int)(tf_bits(kl0, kl1, base + 1u) & 1u);
  }
  row = min(max(row, 0), NN - 1);
  col = min(max(col, 0), NN - 1);
  const int packed = (row << 16) | col;
  pk[lane] = packed;
  __syncthreads();

  bool dup = false;
  for (int p2 = 0; p2 < lane; p2++)
    if (pk[p2] == packed) dup = true;

  const float frow = (float)row, fcol = (float)col;
  float dens[K_];
#pragma unroll
  for (int qd = 0; qd < K_; qd++) {
    const float dx = (frow - meanv[qd]) * invsig[qd];
    const float dy = (fcol - meanv[qd]) * invsig[qd];
    dens[qd] = dup ? 0.f : expf(-0.5f * (dx * dx + dy * dy));
  }
  float wsum = 0.f;
#pragma unroll
  for (int qd = 0; qd < K_; qd++) {
    float s = dens[qd];
    for (int d = 1; d < 64; d <<= 1) s += __shfl_xor(s, d);
    wsum += dens[qd] / s;
  }
  const float w = mvalues[n] * wsum;

  prc[(size_t)bn * NPTS_ + lane] = packed;
  pw[(size_t)bn * NPTS_ + lane] = w;
  atomicAdd(&counts[b * NN + row], 1);
}

// ---------------- K3: per-b exclusive scan of row counts ----------------
__global__ void scan_kernel(const int* __restrict__ counts,
                            int* __restrict__ offs, int* __restrict__ cursor) {
  __shared__ int sd[NN];
  const int b = blockIdx.x, t = threadIdx.x; // 1024 threads
  const int v = counts[b * NN + t];
  sd[t] = v;
  __syncthreads();
  for (int d = 1; d < NN; d <<= 1) {
    const int add = (t >= d) ? sd[t - d] : 0;
    __syncthreads();
    sd[t] += add;
    __syncthreads();
  }
  const int excl = sd[t] - v;
  offs[b * NN + t] = excl;
  cursor[b * NN + t] = excl;
}

// ---------------- K4: scatter entries into row-sorted order ----------------
__global__ void scatter_kernel(const int* __restrict__ prc, const float* __restrict__ pw,
                               int* __restrict__ cursor,
                               int* __restrict__ scol, float* __restrict__ sw) {
  const int bn = blockIdx.x;
  const int b = bn >> 10;
  const size_t i = (size_t)bn * NPTS_ + threadIdx.x;
  const int packed = prc[i];
  const int row = packed >> 16, col = packed & 0xFFFF;
  const int pos = atomicAdd(&cursor[b * NN + row], 1);
  scol[(size_t)b * (NN * NPTS_) + pos] = col;
  sw[(size_t)b * (NN * NPTS_) + pos] = pw[i];
}

// ---------------- K5: chunked two-phase flash segment softmax ----------------
// block -> (b,row) via XCD swizzle: XCD = blockIdx%8 (round-robin dispatch),
// b = XCD/2, so each XCD's L2 only holds one batch's K/V (4 MB ~= L2 size).
// Phase A: lane=entry (gather K row, one expf). Stage p/col to LDS.
// Phase B: lane=dim, fixed-64 unrolled loop, uniform LDS broadcast + coalesced
// V-row loads -> compiler can batch-issue loads (ILP).
__global__ void __launch_bounds__(512) attn_kernel(
    const float* __restrict__ q, const float* __restrict__ k, const float* __restrict__ v,
    const int* __restrict__ offs, const int* __restrict__ counts,
    const int* __restrict__ scol, const float* __restrict__ sw,
    float* __restrict__ attn) {
  __shared__ float qs[NH_][EMB_];
  __shared__ float ps_lds[NH_][64];
  __shared__ int   cs_lds[NH_][64];

  const int xcd = blockIdx.x & 7;
  const int rank = blockIdx.x >> 3;        // 0..511
  const int b = xcd >> 1;                  // 2 XCDs per batch
  const int row = (rank << 1) | (xcd & 1); // 0..1023

  const int h = threadIdx.x >> 6, lane = threadIdx.x & 63;
  const int bh = b * NH_ + h;

  const float* __restrict__ kb = k + (size_t)bh * NN * EMB_;
  const float* __restrict__ vb = v + (size_t)bh * NN * EMB_;
  const int* __restrict__ sc = scol + (size_t)b * (NN * NPTS_);
  const float* __restrict__ swp = sw + (size_t)b * (NN * NPTS_);

  qs[h][lane] = q[((size_t)bh * NN + row) * EMB_ + lane];
  const int start = offs[b * NN + row];
  const int len = counts[b * NN + row];
  __syncthreads();

  float m = -INFINITY, Z = 0.f, acc = 0.f;

  for (int cb = 0; cb < len; cb += 64) {
    const int e = cb + lane;
    float logit = -INFINITY;
    int col = 0;
    if (e < len) {
      col = sc[start + e];
      const float wv = swp[start + e];
      const float4* __restrict__ kp = (const float4*)(kb + (size_t)col * EMB_);
      const float4* __restrict__ qp = (const float4*)qs[h];
      float dot = 0.f;
#pragma unroll
      for (int i = 0; i < 16; i++) {
        const float4 a4 = qp[i];
        const float4 b4 = kp[i];
        dot += a4.x * b4.x + a4.y * b4.y + a4.z * b4.z + a4.w * b4.w;
      }
      logit = wv * dot;
    }
    // chunk max over 64 lanes
    float cm = logit;
#pragma unroll
    for (int d = 1; d < 64; d <<= 1) cm = fmaxf(cm, __shfl_xor(cm, d));
    const float nm = fmaxf(m, cm);
    const float scale = expf(m - nm);            // 0 when m was -inf
    const float p = expf(logit - nm);            // 0 for e >= len (logit=-inf)
    float zs = p;
#pragma unroll
    for (int d = 1; d < 64; d <<= 1) zs += __shfl_xor(zs, d);
    Z = Z * scale + zs;
    m = nm;

    // stage p/col for this wave (wave-private LDS slice; no barrier needed)
    ps_lds[h][lane] = p;
    cs_lds[h][lane] = col;

    // Phase B: lane = dim, compile-time 64 iterations (zero-padded p)
    acc *= scale;
#pragma unroll
    for (int ee = 0; ee < 64; ee++) {
      const float pe = ps_lds[h][ee];   // uniform address -> LDS broadcast
      const int   ce = cs_lds[h][ee];
      acc += pe * vb[(size_t)ce * EMB_ + lane];
    }
  }

  const float o = (len > 0) ? acc / Z : 0.f;
  attn[((size_t)bh * NN + row) * EMB_ + lane] = o;
}

// ---------------- K6: output projection ----------------
#define ROWS6 8
__global__ void out_kernel(const float* __restrict__ attn,
                           const float* __restrict__ Wu, const float* __restrict__ bu,
                           float* __restrict__ out) {
  __shared__ float a[ROWS6][NH_ * EMB_];
  const int base = blockIdx.x * ROWS6;
  const int lane = threadIdx.x; // 64
  for (int r = 0; r < ROWS6; r++) {
    const int bn = base + r;
    const int b = bn >> 10, n = bn & 1023;
    for (int h = 0; h < NH_; h++)
      a[r][h * EMB_ + lane] = attn[((size_t)(b * NH_ + h) * NN + n) * EMB_ + lane];
  }
  __syncthreads();
  float acc[ROWS6];
#pragma unroll
  for (int r = 0; r < ROWS6; r++) acc[r] = bu[lane];
  for (int c = 0; c < NH_ * EMB_; c++) {
    const float wv = Wu[c * EMB_ + lane];
#pragma unroll
    for (int r = 0; r < ROWS6; r++) acc[r] += a[r][c] * wv;
  }
  for (int r = 0; r < ROWS6; r++) out[(size_t)(base + r) * EMB_ + lane] = acc[r];
}

// ---------------- host ----------------
extern "C" void kernel_launch(void* const* d_in, const int* in_sizes, int n_in,
                              void* d_out, int out_size, void* d_ws, size_t ws_size,
                              hipStream_t stream) {
  const float* x   = (const float*)d_in[0];
  const float* Wq  = (const float*)d_in[1];
  const float* Wk  = (const float*)d_in[2];
  const float* Wv  = (const float*)d_in[3];
  const float* Wu  = (const float*)d_in[4];
  const float* bu  = (const float*)d_in[5];
  const float* Wp1 = (const float*)d_in[6];
  const float* bp1 = (const float*)d_in[7];
  const float* Wp2 = (const float*)d_in[8];
  const float* bp2 = (const float*)d_in[9];
  const float* mv  = (const float*)d_in[10];
  float* out = (float*)d_out;

  char* ws = (char*)d_ws;
  size_t off = 0;
  auto alloc = [&](size_t bytes) -> void* {
    void* p = ws + off;
    off += (bytes + 255) & ~(size_t)255;
    return p;
  };
  const size_t QKV = (size_t)BH_ * NN * EMB_ * sizeof(float); // 8 MB
  float* q    = (float*)alloc(QKV);
  float* k    = (float*)alloc(QKV);
  float* v    = (float*)alloc(QKV);
  float* attn = (float*)alloc(QKV);
  int*   prc  = (int*)  alloc((size_t)BB * NN * NPTS_ * sizeof(int));
  float* pw   = (float*)alloc((size_t)BB * NN * NPTS_ * sizeof(float));
  int*   counts = (int*)alloc((size_t)BB * NN * sizeof(int));
  int*   offsA  = (int*)alloc((size_t)BB * NN * sizeof(int));
  int*   cursor = (int*)alloc((size_t)BB * NN * sizeof(int));
  int*   scol = (int*)  alloc((size_t)BB * NN * NPTS_ * sizeof(int));
  float* sw   = (float*)alloc((size_t)BB * NN * NPTS_ * sizeof(float));
  if (off > ws_size) return;

  uint32_t kgA, kgB, klA, klB;
  tf2x32(0u, 42u, 0u, 0u, kgA, kgB);  // kg
  tf2x32(0u, 42u, 0u, 1u, klA, klB);  // kl
  uint32_t kg2A, kg2B, kl2A, kl2B;
  tf2x32(kgA, kgB, 0u, 1u, kg2A, kg2B); // split(kg)[1]
  tf2x32(klA, klB, 0u, 1u, kl2A, kl2B); // split(kl)[1]

  hipMemsetAsync(counts, 0, (size_t)BB * NN * sizeof(int), stream);

  qkv_kernel<<<(BB * NN) / ROWS1, 256, 0, stream>>>(x, Wq, Wk, Wv, q, k, v);
  points_kernel<<<BB * NN, 64, 0, stream>>>(x, Wp1, bp1, Wp2, bp2, mv,
                                            prc, pw, counts, kg2A, kg2B, kl2A, kl2B);
  scan_kernel<<<BB, NN, 0, stream>>>(counts, offsA, cursor);
  scatter_kernel<<<BB * NN, NPTS_, 0, stream>>>(prc, pw, cursor, scol, sw);
  attn_kernel<<<BB * NN, 512, 0, stream>>>(q, k, v, offsA, counts, scol, sw, attn);
  out_kernel<<<(BB * NN) / ROWS6, 64, 0, stream>>>(attn, Wu, bu, out);
}

// Round 4
// 233.632 us; speedup vs baseline: 1.5472x; 1.1722x over previous
//
#include <hip/hip_runtime.h>
#include <cstdint>
#include <cstddef>

#define BB 4
#define NN 1024
#define EMB_ 64
#define NH_ 8
#define BH_ (BB*NH_)
#define HID_ 256
#define K_ 8
#define NPTS_ 64
#define QB 512  // qkv blocks inside pre_kernel

// ---------------- threefry2x32 (JAX-compatible, 20 rounds) ----------------
__host__ __device__ inline void tf2x32(uint32_t k0, uint32_t k1, uint32_t c0, uint32_t c1,
                                       uint32_t &o0, uint32_t &o1) {
  uint32_t ks2 = k0 ^ k1 ^ 0x1BD11BDAu;
  uint32_t x0 = c0 + k0, x1 = c1 + k1;
#define TFR(r) { x0 += x1; x1 = (x1 << (r)) | (x1 >> (32 - (r))); x1 ^= x0; }
  TFR(13) TFR(15) TFR(26) TFR(6)
  x0 += k1;  x1 += ks2 + 1u;
  TFR(17) TFR(29) TFR(16) TFR(24)
  x0 += ks2; x1 += k0 + 2u;
  TFR(13) TFR(15) TFR(26) TFR(6)
  x0 += k0;  x1 += k1 + 3u;
  TFR(17) TFR(29) TFR(16) TFR(24)
  x0 += k1;  x1 += ks2 + 4u;
  TFR(13) TFR(15) TFR(26) TFR(6)
  x0 += ks2; x1 += k0 + 5u;
#undef TFR
  o0 = x0; o1 = x1;
}

__device__ inline uint32_t tf_bits(uint32_t k0, uint32_t k1, uint32_t idx) {
  uint32_t a, b;
  tf2x32(k0, k1, 0u, idx, a, b);
  return a ^ b;
}

__device__ inline float softplusf(float v) {
  return fmaxf(v, 0.f) + log1pf(expf(-fabsf(v)));
}

// ---------------- K1: fused QKV projection + MLP/points ----------------
#define ROWS1 8
__global__ void __launch_bounds__(256) pre_kernel(
    const float* __restrict__ x,
    const float* __restrict__ Wq, const float* __restrict__ Wk, const float* __restrict__ Wv,
    const float* __restrict__ Wp1, const float* __restrict__ bp1,
    const float* __restrict__ Wp2, const float* __restrict__ bp2,
    const float* __restrict__ mvalues,
    float* __restrict__ q, float* __restrict__ k, float* __restrict__ v,
    int* __restrict__ prc, float* __restrict__ pw,
    uint32_t kg0, uint32_t kg1, uint32_t kl0, uint32_t kl1) {
  // ---- qkv part LDS ----
  __shared__ float xq[ROWS1][EMB_];
  // ---- points part LDS (4 rows per block, one per wave) ----
  __shared__ float xs[4][EMB_];
  __shared__ float hs[4][HID_];
  __shared__ float ps[4][16];
  __shared__ float meanv[4][K_], invsig[4][K_];
  __shared__ int flv[4][K_];
  __shared__ int pk[4][NPTS_];

  if (blockIdx.x < QB) {
    // ================= QKV =================
    const int block0 = blockIdx.x * ROWS1;
    const int t = threadIdx.x;
    for (int i = t; i < ROWS1 * EMB_; i += 256) xq[i / EMB_][i % EMB_] = x[(size_t)block0 * EMB_ + i];
    __syncthreads();
    const float qkscale = 0.3535533905932738f; // 64^-0.25

    auto dmat = [&](const float* __restrict__ W, float* __restrict__ o, float sc) {
      for (int half = 0; half < 2; half++) {
        const int c = half * 256 + t;
        float acc[ROWS1];
#pragma unroll
        for (int r = 0; r < ROWS1; r++) acc[r] = 0.f;
        for (int i = 0; i < EMB_; i++) {
          const float wv = W[i * 512 + c];
#pragma unroll
          for (int r = 0; r < ROWS1; r++) acc[r] += xq[r][i] * wv;
        }
        const int h = c >> 6, j = c & 63;
#pragma unroll
        for (int r = 0; r < ROWS1; r++) {
          const int gr = block0 + r;
          const int b = gr >> 10, n = gr & 1023;
          o[(((size_t)(b * NH_ + h) * NN + n)) * EMB_ + j] = acc[r] * sc;
        }
      }
    };
    dmat(Wq, q, qkscale);
    dmat(Wk, k, qkscale);
    dmat(Wv, v, 1.0f);
    return;
  }

  // ================= points (4 bn per block) =================
  const int w = threadIdx.x >> 6, lane = threadIdx.x & 63;
  const int bn = (blockIdx.x - QB) * 4 + w;
  const int n = bn & 1023;

  xs[w][lane] = x[(size_t)bn * EMB_ + lane];
  __syncthreads();

#pragma unroll
  for (int cc = 0; cc < 4; cc++) {
    const int c = cc * 64 + lane;
    float a = bp1[c];
    for (int i = 0; i < EMB_; i++) a += xs[w][i] * Wp1[i * HID_ + c];
    hs[w][c] = fmaxf(a, 0.f);
  }
  __syncthreads();

  if (lane < 16) {
    float a = bp2[lane];
    for (int c = 0; c < HID_; c++) a += hs[w][c] * Wp2[c * 16 + lane];
    ps[w][lane] = a;
  }
  __syncthreads();

  if (lane < K_) {
    const float rm = ps[w][lane], rs = ps[w][K_ + lane];
    float mean = (float)n - softplusf(rm);
    mean = fminf(fmaxf(mean, 0.f), (float)(NN - 1));
    const float sig = softplusf(rs + 2.0f) + 1e-6f;
    meanv[w][lane] = mean;
    invsig[w][lane] = 1.f / sig;
    flv[w][lane] = (int)floorf(mean);
  }
  __syncthreads();

  const int kk = lane >> 3, j = lane & 7;
  const int fl = flv[w][kk];
  int row, col;
  if (j < 4) {
    row = fl + (j >> 1);
    col = fl + (j & 1);
  } else if (j < 6) {
    const int g = j - 4;
    const uint32_t base = ((uint32_t)(bn * K_ + kk) * 2u + (uint32_t)g) * 2u;
    row = (int)(tf_bits(kg0, kg1, base + 0u) & 1023u);
    col = (int)(tf_bits(kg0, kg1, base + 1u) & 1023u);
  } else {
    const int a = j - 6;
    const uint32_t base = ((uint32_t)(bn * K_ + kk) * 2u + (uint32_t)a) * 2u;
    row = fl - 1 + (int)(tf_bits(kl0, kl1, base + 0u) & 1u);
    col = fl - 1 + (int)(tf_bits(kl0, kl1, base + 1u) & 1u);
  }
  row = min(max(row, 0), NN - 1);
  col = min(max(col, 0), NN - 1);
  const int packed = (row << 16) | col;
  pk[w][lane] = packed;
  __syncthreads();

  bool dup = false;
  for (int p2 = 0; p2 < lane; p2++)
    if (pk[w][p2] == packed) dup = true;

  const float frow = (float)row, fcol = (float)col;
  float dens[K_];
#pragma unroll
  for (int qd = 0; qd < K_; qd++) {
    const float dx = (frow - meanv[w][qd]) * invsig[w][qd];
    const float dy = (fcol - meanv[w][qd]) * invsig[w][qd];
    dens[qd] = dup ? 0.f : expf(-0.5f * (dx * dx + dy * dy));
  }
  float wsum = 0.f;
#pragma unroll
  for (int qd = 0; qd < K_; qd++) {
    float s = dens[qd];
    for (int d = 1; d < 64; d <<= 1) s += __shfl_xor(s, d);
    wsum += dens[qd] / s;
  }
  const float wgt = mvalues[n] * wsum;

  prc[(size_t)bn * NPTS_ + lane] = packed;
  pw[(size_t)bn * NPTS_ + lane] = wgt;
}

// ---------------- K2: histogram + scan + scatter (per batch) ----------------
__global__ void __launch_bounds__(1024) mid_kernel(
    const int* __restrict__ prc, const float* __restrict__ pw,
    int* __restrict__ offs, int* __restrict__ counts,
    int* __restrict__ scol, float* __restrict__ sw) {
  __shared__ int hist[NN];
  __shared__ int sd[NN];
  __shared__ int cur[NN];
  const int b = blockIdx.x, t = threadIdx.x;
  const int* __restrict__ prcB = prc + (size_t)b * (NN * NPTS_);
  const float* __restrict__ pwB = pw + (size_t)b * (NN * NPTS_);
  int* __restrict__ scolB = scol + (size_t)b * (NN * NPTS_);
  float* __restrict__ swB = sw + (size_t)b * (NN * NPTS_);

  hist[t] = 0;
  __syncthreads();
  // coalesced: entry e = j*1024 + t
  for (int j = 0; j < 64; j++)
    atomicAdd(&hist[prcB[j * NN + t] >> 16], 1);
  __syncthreads();

  const int vc = hist[t];
  sd[t] = vc;
  __syncthreads();
  for (int d = 1; d < NN; d <<= 1) {
    const int add = (t >= d) ? sd[t - d] : 0;
    __syncthreads();
    sd[t] += add;
    __syncthreads();
  }
  const int excl = sd[t] - vc;
  offs[b * NN + t] = excl;
  counts[b * NN + t] = vc;
  cur[t] = excl;
  __syncthreads();

  for (int j = 0; j < 64; j++) {
    const int e = j * NN + t;
    const int pkd = prcB[e];
    const int row = pkd >> 16;
    const int pos = atomicAdd(&cur[row], 1);
    scolB[pos] = pkd & 0xFFFF;
    swB[pos] = pwB[e];
  }
}

// ---------------- K3: flash segment softmax + fused output projection ------
// block -> (b,row) via XCD swizzle; 8 waves = 8 heads. After attention, the
// block holds all 8 head outputs for this row -> fuse out = a @ Wu + bu.
__global__ void __launch_bounds__(512) attn_out_kernel(
    const float* __restrict__ q, const float* __restrict__ k, const float* __restrict__ v,
    const int* __restrict__ offs, const int* __restrict__ counts,
    const int* __restrict__ scol, const float* __restrict__ sw,
    const float* __restrict__ Wu, const float* __restrict__ bu,
    float* __restrict__ out) {
  __shared__ float qs[NH_][EMB_];
  __shared__ float ps_lds[NH_][64];
  __shared__ int   cs_lds[NH_][64];
  __shared__ float ao[NH_][EMB_];
  __shared__ float op[NH_][EMB_];

  const int xcd = blockIdx.x & 7;
  const int rank = blockIdx.x >> 3;        // 0..511
  const int b = xcd >> 1;                  // 2 XCDs per batch
  const int row = (rank << 1) | (xcd & 1); // 0..1023

  const int h = threadIdx.x >> 6, lane = threadIdx.x & 63;
  const int bh = b * NH_ + h;

  const float* __restrict__ kb = k + (size_t)bh * NN * EMB_;
  const float* __restrict__ vb = v + (size_t)bh * NN * EMB_;
  const int* __restrict__ sc = scol + (size_t)b * (NN * NPTS_);
  const float* __restrict__ swp = sw + (size_t)b * (NN * NPTS_);

  qs[h][lane] = q[((size_t)bh * NN + row) * EMB_ + lane];
  const int start = offs[b * NN + row];
  const int len = counts[b * NN + row];
  __syncthreads();

  float m = -INFINITY, Z = 0.f, acc = 0.f;

  for (int cb = 0; cb < len; cb += 64) {
    const int e = cb + lane;
    float logit = -INFINITY;
    int col = 0;
    if (e < len) {
      col = sc[start + e];
      const float wv = swp[start + e];
      const float4* __restrict__ kp = (const float4*)(kb + (size_t)col * EMB_);
      const float4* __restrict__ qp = (const float4*)qs[h];
      float dot = 0.f;
#pragma unroll
      for (int i = 0; i < 16; i++) {
        const float4 a4 = qp[i];
        const float4 b4 = kp[i];
        dot += a4.x * b4.x + a4.y * b4.y + a4.z * b4.z + a4.w * b4.w;
      }
      logit = wv * dot;
    }
    float cm = logit;
#pragma unroll
    for (int d = 1; d < 64; d <<= 1) cm = fmaxf(cm, __shfl_xor(cm, d));
    const float nm = fmaxf(m, cm);
    const float scale = expf(m - nm);            // 0 when m was -inf
    const float p = expf(logit - nm);            // 0 for e >= len
    float zs = p;
#pragma unroll
    for (int d = 1; d < 64; d <<= 1) zs += __shfl_xor(zs, d);
    Z = Z * scale + zs;
    m = nm;

    ps_lds[h][lane] = p;
    cs_lds[h][lane] = col;

    acc *= scale;
    const int lim = len - cb; // entries this chunk (may exceed 64; capped by groups)
#pragma unroll
    for (int g = 0; g < 8; g++) {
      if (g * 8 < lim) {
#pragma unroll
        for (int u = 0; u < 8; u++) {
          const int ee = g * 8 + u;
          acc += ps_lds[h][ee] * vb[(size_t)cs_lds[h][ee] * EMB_ + lane];
        }
      }
    }
  }

  ao[h][lane] = (len > 0) ? acc / Z : 0.f;
  __syncthreads();

  // out[row] = concat_h(ao) @ Wu + bu ; wave h covers rows h*64..h*64+63 of Wu
  float s = 0.f;
  const float* __restrict__ wu_h = Wu + (size_t)(h * 64) * EMB_;
#pragma unroll
  for (int d = 0; d < 64; d++)
    s += ao[h][d] * wu_h[d * EMB_ + lane];
  op[h][lane] = s;
  __syncthreads();

  if (h == 0) {
    float t = bu[lane];
#pragma unroll
    for (int hh = 0; hh < NH_; hh++) t += op[hh][lane];
    out[(size_t)(b * NN + row) * EMB_ + lane] = t;
  }
}

// ---------------- host ----------------
extern "C" void kernel_launch(void* const* d_in, const int* in_sizes, int n_in,
                              void* d_out, int out_size, void* d_ws, size_t ws_size,
                              hipStream_t stream) {
  const float* x   = (const float*)d_in[0];
  const float* Wq  = (const float*)d_in[1];
  const float* Wk  = (const float*)d_in[2];
  const float* Wv  = (const float*)d_in[3];
  const float* Wu  = (const float*)d_in[4];
  const float* bu  = (const float*)d_in[5];
  const float* Wp1 = (const float*)d_in[6];
  const float* bp1 = (const float*)d_in[7];
  const float* Wp2 = (const float*)d_in[8];
  const float* bp2 = (const float*)d_in[9];
  const float* mv  = (const float*)d_in[10];
  float* out = (float*)d_out;

  char* ws = (char*)d_ws;
  size_t off = 0;
  auto alloc = [&](size_t bytes) -> void* {
    void* p = ws + off;
    off += (bytes + 255) & ~(size_t)255;
    return p;
  };
  const size_t QKV = (size_t)BH_ * NN * EMB_ * sizeof(float); // 8 MB
  float* q    = (float*)alloc(QKV);
  float* k    = (float*)alloc(QKV);
  float* v    = (float*)alloc(QKV);
  int*   prc  = (int*)  alloc((size_t)BB * NN * NPTS_ * sizeof(int));
  float* pw   = (float*)alloc((size_t)BB * NN * NPTS_ * sizeof(float));
  int*   counts = (int*)alloc((size_t)BB * NN * sizeof(int));
  int*   offsA  = (int*)alloc((size_t)BB * NN * sizeof(int));
  int*   scol = (int*)  alloc((size_t)BB * NN * NPTS_ * sizeof(int));
  float* sw   = (float*)alloc((size_t)BB * NN * NPTS_ * sizeof(float));
  if (off > ws_size) return;

  uint32_t kgA, kgB, klA, klB;
  tf2x32(0u, 42u, 0u, 0u, kgA, kgB);  // kg
  tf2x32(0u, 42u, 0u, 1u, klA, klB);  // kl
  uint32_t kg2A, kg2B, kl2A, kl2B;
  tf2x32(kgA, kgB, 0u, 1u, kg2A, kg2B); // split(kg)[1]
  tf2x32(klA, klB, 0u, 1u, kl2A, kl2B); // split(kl)[1]

  pre_kernel<<<QB + (BB * NN) / 4, 256, 0, stream>>>(
      x, Wq, Wk, Wv, Wp1, bp1, Wp2, bp2, mv, q, k, v, prc, pw,
      kg2A, kg2B, kl2A, kl2B);
  mid_kernel<<<BB, 1024, 0, stream>>>(prc, pw, offsA, counts, scol, sw);
  attn_out_kernel<<<BB * NN, 512, 0, stream>>>(q, k, v, offsA, counts, scol, sw,
                                               Wu, bu, out);
}

// Round 5
// 191.736 us; speedup vs baseline: 1.8852x; 1.2185x over previous
//
#include <hip/hip_runtime.h>
#include <hip/hip_fp16.h>
#include <cstdint>
#include <cstddef>

#define BB 4
#define NN 1024
#define EMB_ 64
#define NH_ 8
#define BH_ (BB*NH_)
#define HID_ 256
#define K_ 8
#define NPTS_ 64
#define QB 512  // qkv blocks inside pre_kernel

// ---------------- threefry2x32 (JAX-compatible, 20 rounds) ----------------
__host__ __device__ inline void tf2x32(uint32_t k0, uint32_t k1, uint32_t c0, uint32_t c1,
                                       uint32_t &o0, uint32_t &o1) {
  uint32_t ks2 = k0 ^ k1 ^ 0x1BD11BDAu;
  uint32_t x0 = c0 + k0, x1 = c1 + k1;
#define TFR(r) { x0 += x1; x1 = (x1 << (r)) | (x1 >> (32 - (r))); x1 ^= x0; }
  TFR(13) TFR(15) TFR(26) TFR(6)
  x0 += k1;  x1 += ks2 + 1u;
  TFR(17) TFR(29) TFR(16) TFR(24)
  x0 += ks2; x1 += k0 + 2u;
  TFR(13) TFR(15) TFR(26) TFR(6)
  x0 += k0;  x1 += k1 + 3u;
  TFR(17) TFR(29) TFR(16) TFR(24)
  x0 += k1;  x1 += ks2 + 4u;
  TFR(13) TFR(15) TFR(26) TFR(6)
  x0 += ks2; x1 += k0 + 5u;
#undef TFR
  o0 = x0; o1 = x1;
}

__device__ inline uint32_t tf_bits(uint32_t k0, uint32_t k1, uint32_t idx) {
  uint32_t a, b;
  tf2x32(k0, k1, 0u, idx, a, b);
  return a ^ b;
}

__device__ inline float softplusf(float v) {
  return fmaxf(v, 0.f) + log1pf(expf(-fabsf(v)));
}

// ---------------- K1: fused QKV projection + MLP/points ----------------
#define ROWS1 8
__global__ void __launch_bounds__(256) pre_kernel(
    const float* __restrict__ x,
    const float* __restrict__ Wq, const float* __restrict__ Wk, const float* __restrict__ Wv,
    const float* __restrict__ Wp1, const float* __restrict__ bp1,
    const float* __restrict__ Wp2, const float* __restrict__ bp2,
    const float* __restrict__ mvalues,
    float* __restrict__ q, __half* __restrict__ k, __half* __restrict__ v,
    int* __restrict__ prc, float* __restrict__ pw,
    uint32_t kg0, uint32_t kg1, uint32_t kl0, uint32_t kl1) {
  __shared__ float xq[ROWS1][EMB_];
  __shared__ float xs[4][EMB_];
  __shared__ float hs[4][HID_];
  __shared__ float ps[4][16];
  __shared__ float meanv[4][K_], invsig[4][K_];
  __shared__ int flv[4][K_];
  __shared__ int pk[4][NPTS_];

  if (blockIdx.x < QB) {
    // ================= QKV =================
    const int block0 = blockIdx.x * ROWS1;
    const int t = threadIdx.x;
    for (int i = t; i < ROWS1 * EMB_; i += 256) xq[i / EMB_][i % EMB_] = x[(size_t)block0 * EMB_ + i];
    __syncthreads();
    const float qkscale = 0.3535533905932738f; // 64^-0.25

    auto dmatf = [&](const float* __restrict__ W, float* __restrict__ o, float sc) {
      for (int half = 0; half < 2; half++) {
        const int c = half * 256 + t;
        float acc[ROWS1];
#pragma unroll
        for (int r = 0; r < ROWS1; r++) acc[r] = 0.f;
        for (int i = 0; i < EMB_; i++) {
          const float wv = W[i * 512 + c];
#pragma unroll
          for (int r = 0; r < ROWS1; r++) acc[r] += xq[r][i] * wv;
        }
        const int h = c >> 6, j = c & 63;
#pragma unroll
        for (int r = 0; r < ROWS1; r++) {
          const int gr = block0 + r;
          const int b = gr >> 10, n = gr & 1023;
          o[(((size_t)(b * NH_ + h) * NN + n)) * EMB_ + j] = acc[r] * sc;
        }
      }
    };
    auto dmath = [&](const float* __restrict__ W, __half* __restrict__ o, float sc) {
      for (int half = 0; half < 2; half++) {
        const int c = half * 256 + t;
        float acc[ROWS1];
#pragma unroll
        for (int r = 0; r < ROWS1; r++) acc[r] = 0.f;
        for (int i = 0; i < EMB_; i++) {
          const float wv = W[i * 512 + c];
#pragma unroll
          for (int r = 0; r < ROWS1; r++) acc[r] += xq[r][i] * wv;
        }
        const int h = c >> 6, j = c & 63;
#pragma unroll
        for (int r = 0; r < ROWS1; r++) {
          const int gr = block0 + r;
          const int b = gr >> 10, n = gr & 1023;
          o[(((size_t)(b * NH_ + h) * NN + n)) * EMB_ + j] = __float2half(acc[r] * sc);
        }
      }
    };
    dmatf(Wq, q, qkscale);
    dmath(Wk, k, qkscale);
    dmath(Wv, v, 1.0f);
    return;
  }

  // ================= points (4 bn per block) =================
  const int w = threadIdx.x >> 6, lane = threadIdx.x & 63;
  const int bn = (blockIdx.x - QB) * 4 + w;
  const int n = bn & 1023;

  xs[w][lane] = x[(size_t)bn * EMB_ + lane];
  __syncthreads();

#pragma unroll
  for (int cc = 0; cc < 4; cc++) {
    const int c = cc * 64 + lane;
    float a = bp1[c];
    for (int i = 0; i < EMB_; i++) a += xs[w][i] * Wp1[i * HID_ + c];
    hs[w][c] = fmaxf(a, 0.f);
  }
  __syncthreads();

  if (lane < 16) {
    float a = bp2[lane];
    for (int c = 0; c < HID_; c++) a += hs[w][c] * Wp2[c * 16 + lane];
    ps[w][lane] = a;
  }
  __syncthreads();

  if (lane < K_) {
    const float rm = ps[w][lane], rs = ps[w][K_ + lane];
    float mean = (float)n - softplusf(rm);
    mean = fminf(fmaxf(mean, 0.f), (float)(NN - 1));
    const float sig = softplusf(rs + 2.0f) + 1e-6f;
    meanv[w][lane] = mean;
    invsig[w][lane] = 1.f / sig;
    flv[w][lane] = (int)floorf(mean);
  }
  __syncthreads();

  const int kk = lane >> 3, j = lane & 7;
  const int fl = flv[w][kk];
  int row, col;
  if (j < 4) {
    row = fl + (j >> 1);
    col = fl + (j & 1);
  } else if (j < 6) {
    const int g = j - 4;
    const uint32_t base = ((uint32_t)(bn * K_ + kk) * 2u + (uint32_t)g) * 2u;
    row = (int)(tf_bits(kg0, kg1, base + 0u) & 1023u);
    col = (int)(tf_bits(kg0, kg1, base + 1u) & 1023u);
  } else {
    const int a = j - 6;
    const uint32_t base = ((uint32_t)(bn * K_ + kk) * 2u + (uint32_t)a) * 2u;
    row = fl - 1 + (int)(tf_bits(kl0, kl1, base + 0u) & 1u);
    col = fl - 1 + (int)(tf_bits(kl0, kl1, base + 1u) & 1u);
  }
  row = min(max(row, 0), NN - 1);
  col = min(max(col, 0), NN - 1);
  const int packed = (row << 16) | col;
  pk[w][lane] = packed;
  __syncthreads();

  bool dup = false;
  for (int p2 = 0; p2 < lane; p2++)
    if (pk[w][p2] == packed) dup = true;

  const float frow = (float)row, fcol = (float)col;
  float dens[K_];
#pragma unroll
  for (int qd = 0; qd < K_; qd++) {
    const float dx = (frow - meanv[w][qd]) * invsig[w][qd];
    const float dy = (fcol - meanv[w][qd]) * invsig[w][qd];
    dens[qd] = dup ? 0.f : expf(-0.5f * (dx * dx + dy * dy));
  }
  float wsum = 0.f;
#pragma unroll
  for (int qd = 0; qd < K_; qd++) {
    float s = dens[qd];
    for (int d = 1; d < 64; d <<= 1) s += __shfl_xor(s, d);
    wsum += dens[qd] / s;
  }
  const float wgt = mvalues[n] * wsum;

  prc[(size_t)bn * NPTS_ + lane] = packed;
  pw[(size_t)bn * NPTS_ + lane] = wgt;
}

// ---------------- K2: histogram + scan + scatter (per batch) ----------------
__global__ void __launch_bounds__(1024) mid_kernel(
    const int* __restrict__ prc, const float* __restrict__ pw,
    int* __restrict__ offs, int* __restrict__ counts,
    int* __restrict__ scol, float* __restrict__ sw) {
  __shared__ int hist[NN];
  __shared__ int cur[NN];
  __shared__ int wsum[16];
  const int b = blockIdx.x, t = threadIdx.x;
  const int lane = t & 63, wid = t >> 6;
  const int* __restrict__ prcB = prc + (size_t)b * (NN * NPTS_);
  const float* __restrict__ pwB = pw + (size_t)b * (NN * NPTS_);
  int* __restrict__ scolB = scol + (size_t)b * (NN * NPTS_);
  float* __restrict__ swB = sw + (size_t)b * (NN * NPTS_);

  hist[t] = 0;
  __syncthreads();
  for (int j = 0; j < 64; j++)
    atomicAdd(&hist[prcB[j * NN + t] >> 16], 1);
  __syncthreads();

  const int vc = hist[t];
  // hierarchical inclusive scan: wave shfl scan + wave-sum scan
  int vsc = vc;
#pragma unroll
  for (int d = 1; d < 64; d <<= 1) {
    const int up = __shfl_up(vsc, d);
    if (lane >= d) vsc += up;
  }
  if (lane == 63) wsum[wid] = vsc;
  __syncthreads();
  if (wid == 0 && lane < 16) {
    int s = wsum[lane];
#pragma unroll
    for (int d = 1; d < 16; d <<= 1) {
      const int up = __shfl_up(s, d);
      if (lane >= d) s += up;
    }
    wsum[lane] = s;
  }
  __syncthreads();
  const int incl = vsc + (wid > 0 ? wsum[wid - 1] : 0);
  const int excl = incl - vc;
  offs[b * NN + t] = excl;
  counts[b * NN + t] = vc;
  cur[t] = excl;
  __syncthreads();

  for (int j = 0; j < 64; j++) {
    const int e = j * NN + t;
    const int pkd = prcB[e];
    const int row = pkd >> 16;
    const int pos = atomicAdd(&cur[row], 1);
    scolB[pos] = pkd & 0xFFFF;
    swB[pos] = pwB[e];
  }
}

// ---------------- K3: flash segment softmax + fused output projection ------
__global__ void __launch_bounds__(512) attn_out_kernel(
    const float* __restrict__ q, const __half* __restrict__ k, const __half* __restrict__ v,
    const int* __restrict__ offs, const int* __restrict__ counts,
    const int* __restrict__ scol, const float* __restrict__ sw,
    const float* __restrict__ Wu, const float* __restrict__ bu,
    float* __restrict__ out) {
  __shared__ float qs[NH_][EMB_];
  __shared__ float ps_lds[NH_][64];
  __shared__ int   cs_lds[NH_][64];
  __shared__ float ao[NH_][EMB_];
  __shared__ float op[NH_][EMB_];

  const int xcd = blockIdx.x & 7;
  const int rank = blockIdx.x >> 3;        // 0..511
  const int b = xcd >> 1;                  // 2 XCDs per batch
  const int row = (rank << 1) | (xcd & 1); // 0..1023

  const int h = threadIdx.x >> 6, lane = threadIdx.x & 63;
  const int bh = b * NH_ + h;

  const __half* __restrict__ kb = k + (size_t)bh * NN * EMB_;
  const __half* __restrict__ vb = v + (size_t)bh * NN * EMB_;
  const int* __restrict__ sc = scol + (size_t)b * (NN * NPTS_);
  const float* __restrict__ swp = sw + (size_t)b * (NN * NPTS_);

  qs[h][lane] = q[((size_t)bh * NN + row) * EMB_ + lane];
  const int start = offs[b * NN + row];
  const int len = counts[b * NN + row];
  __syncthreads();

  float m = -INFINITY, Z = 0.f, acc = 0.f;

  for (int cb = 0; cb < len; cb += 64) {
    const int e = cb + lane;
    float logit = -INFINITY;
    int col = 0;
    if (e < len) {
      col = sc[start + e];
      const float wv = swp[start + e];
      // K row: 64 halves = 128 B = 8 x float4-sized chunks of 8 halves
      const float4* __restrict__ kp4 = (const float4*)(kb + (size_t)col * EMB_);
      const float4* __restrict__ qp = (const float4*)qs[h];
      float dot = 0.f;
#pragma unroll
      for (int i = 0; i < 8; i++) {
        const float4 raw = kp4[i];
        const __half2* h2 = (const __half2*)&raw;   // 4 half2 = 8 halves
        const float4 qa = qp[i * 2];
        const float4 qb2 = qp[i * 2 + 1];
        const float2 f0 = __half22float2(h2[0]);
        const float2 f1 = __half22float2(h2[1]);
        const float2 f2 = __half22float2(h2[2]);
        const float2 f3 = __half22float2(h2[3]);
        dot += qa.x * f0.x + qa.y * f0.y + qa.z * f1.x + qa.w * f1.y;
        dot += qb2.x * f2.x + qb2.y * f2.y + qb2.z * f3.x + qb2.w * f3.y;
      }
      logit = wv * dot;
    }
    float cm = logit;
#pragma unroll
    for (int d = 1; d < 64; d <<= 1) cm = fmaxf(cm, __shfl_xor(cm, d));
    const float nm = fmaxf(m, cm);
    const float scale = expf(m - nm);            // 0 when m was -inf
    const float p = expf(logit - nm);            // 0 for e >= len
    float zs = p;
#pragma unroll
    for (int d = 1; d < 64; d <<= 1) zs += __shfl_xor(zs, d);
    Z = Z * scale + zs;
    m = nm;

    ps_lds[h][lane] = p;
    cs_lds[h][lane] = col;

    acc *= scale;
    const int lim = len - cb;
#pragma unroll
    for (int g = 0; g < 8; g++) {
      if (g * 8 < lim) {
#pragma unroll
        for (int u = 0; u < 8; u++) {
          const int ee = g * 8 + u;
          acc += ps_lds[h][ee] * __half2float(vb[(size_t)cs_lds[h][ee] * EMB_ + lane]);
        }
      }
    }
  }

  ao[h][lane] = (len > 0) ? acc / Z : 0.f;
  __syncthreads();

  float s = 0.f;
  const float* __restrict__ wu_h = Wu + (size_t)(h * 64) * EMB_;
#pragma unroll
  for (int d = 0; d < 64; d++)
    s += ao[h][d] * wu_h[d * EMB_ + lane];
  op[h][lane] = s;
  __syncthreads();

  if (h == 0) {
    float t = bu[lane];
#pragma unroll
    for (int hh = 0; hh < NH_; hh++) t += op[hh][lane];
    out[(size_t)(b * NN + row) * EMB_ + lane] = t;
  }
}

// ---------------- host ----------------
extern "C" void kernel_launch(void* const* d_in, const int* in_sizes, int n_in,
                              void* d_out, int out_size, void* d_ws, size_t ws_size,
                              hipStream_t stream) {
  const float* x   = (const float*)d_in[0];
  const float* Wq  = (const float*)d_in[1];
  const float* Wk  = (const float*)d_in[2];
  const float* Wv  = (const float*)d_in[3];
  const float* Wu  = (const float*)d_in[4];
  const float* bu  = (const float*)d_in[5];
  const float* Wp1 = (const float*)d_in[6];
  const float* bp1 = (const float*)d_in[7];
  const float* Wp2 = (const float*)d_in[8];
  const float* bp2 = (const float*)d_in[9];
  const float* mv  = (const float*)d_in[10];
  float* out = (float*)d_out;

  char* ws = (char*)d_ws;
  size_t off = 0;
  auto alloc = [&](size_t bytes) -> void* {
    void* p = ws + off;
    off += (bytes + 255) & ~(size_t)255;
    return p;
  };
  const size_t QF = (size_t)BH_ * NN * EMB_ * sizeof(float);   // 8 MB
  const size_t QH = (size_t)BH_ * NN * EMB_ * sizeof(__half);  // 4 MB
  float*  q   = (float*) alloc(QF);
  __half* k   = (__half*)alloc(QH);
  __half* v   = (__half*)alloc(QH);
  int*   prc  = (int*)  alloc((size_t)BB * NN * NPTS_ * sizeof(int));
  float* pw   = (float*)alloc((size_t)BB * NN * NPTS_ * sizeof(float));
  int*   counts = (int*)alloc((size_t)BB * NN * sizeof(int));
  int*   offsA  = (int*)alloc((size_t)BB * NN * sizeof(int));
  int*   scol = (int*)  alloc((size_t)BB * NN * NPTS_ * sizeof(int));
  float* sw   = (float*)alloc((size_t)BB * NN * NPTS_ * sizeof(float));
  if (off > ws_size) return;

  uint32_t kgA, kgB, klA, klB;
  tf2x32(0u, 42u, 0u, 0u, kgA, kgB);  // kg
  tf2x32(0u, 42u, 0u, 1u, klA, klB);  // kl
  uint32_t kg2A, kg2B, kl2A, kl2B;
  tf2x32(kgA, kgB, 0u, 1u, kg2A, kg2B); // split(kg)[1]
  tf2x32(klA, klB, 0u, 1u, kl2A, kl2B); // split(kl)[1]

  pre_kernel<<<QB + (BB * NN) / 4, 256, 0, stream>>>(
      x, Wq, Wk, Wv, Wp1, bp1, Wp2, bp2, mv, q, k, v, prc, pw,
      kg2A, kg2B, kl2A, kl2B);
  mid_kernel<<<BB, 1024, 0, stream>>>(prc, pw, offsA, counts, scol, sw);
  attn_out_kernel<<<BB * NN, 512, 0, stream>>>(q, k, v, offsA, counts, scol, sw,
                                               Wu, bu, out);
}